// Round 12
// baseline (1785.488 us; speedup 1.0000x reference)
//
#include <hip/hip_runtime.h>
#include <hip/hip_cooperative_groups.h>
#include <cstdint>
#include <cstddef>

typedef __attribute__((ext_vector_type(8))) short short8;   // 8 bf16 (4 VGPRs) MFMA frag
typedef __attribute__((ext_vector_type(4))) float floatx4;  // MFMA accumulator

#define T_STEPS 128
#define BATCH   256
#define IDIM    512
#define HDIM    512
#define KHIST   32
#define RDEPTH  16

// LDS layout
#define WA_STRIDE 520      // 512 + 8 pad
#define WB_STRIDE 1032     // 1024 + 8 pad
#define LDS_BYTES 148480   // B: WB 64*1032*2 + EX 16384; A: 49920 + 65536

__device__ __forceinline__ unsigned short f2bf(float x) {
  union { float f; unsigned u; } v; v.f = x;
  unsigned r = v.u + 0x7fffu + ((v.u >> 16) & 1u);   // RNE
  return (unsigned short)(r >> 16);
}
__device__ __forceinline__ float bf2f(unsigned short s) {
  union { unsigned u; float f; } v; v.u = ((unsigned)s) << 16; return v.f;
}
__device__ __forceinline__ float sigm(float x) { return 1.0f / (1.0f + __expf(-x)); }
__device__ __forceinline__ float tanh_f(float x) {
  float ax = fabsf(x);
  float e = __expf(-2.0f * ax);
  float t = (1.0f - e) / (1.0f + e);
  return x < 0.0f ? -t : t;
}

// ---- LLC-coherent exchange (round-6/10 proven protocol, no fences) ----
__device__ __forceinline__ void llc_load_1k(const unsigned short* p, short8* r) {
  asm volatile(
    "global_load_dwordx4 %0,  %16, off sc0 sc1\n\t"
    "global_load_dwordx4 %1,  %16, off offset:64 sc0 sc1\n\t"
    "global_load_dwordx4 %2,  %16, off offset:128 sc0 sc1\n\t"
    "global_load_dwordx4 %3,  %16, off offset:192 sc0 sc1\n\t"
    "global_load_dwordx4 %4,  %16, off offset:256 sc0 sc1\n\t"
    "global_load_dwordx4 %5,  %16, off offset:320 sc0 sc1\n\t"
    "global_load_dwordx4 %6,  %16, off offset:384 sc0 sc1\n\t"
    "global_load_dwordx4 %7,  %16, off offset:448 sc0 sc1\n\t"
    "global_load_dwordx4 %8,  %16, off offset:512 sc0 sc1\n\t"
    "global_load_dwordx4 %9,  %16, off offset:576 sc0 sc1\n\t"
    "global_load_dwordx4 %10, %16, off offset:640 sc0 sc1\n\t"
    "global_load_dwordx4 %11, %16, off offset:704 sc0 sc1\n\t"
    "global_load_dwordx4 %12, %16, off offset:768 sc0 sc1\n\t"
    "global_load_dwordx4 %13, %16, off offset:832 sc0 sc1\n\t"
    "global_load_dwordx4 %14, %16, off offset:896 sc0 sc1\n\t"
    "global_load_dwordx4 %15, %16, off offset:960 sc0 sc1\n\t"
    "s_waitcnt vmcnt(0)"
    : "=&v"(r[0]), "=&v"(r[1]), "=&v"(r[2]), "=&v"(r[3]),
      "=&v"(r[4]), "=&v"(r[5]), "=&v"(r[6]), "=&v"(r[7]),
      "=&v"(r[8]), "=&v"(r[9]), "=&v"(r[10]), "=&v"(r[11]),
      "=&v"(r[12]), "=&v"(r[13]), "=&v"(r[14]), "=&v"(r[15])
    : "v"(p)
    : "memory");
}
__device__ __forceinline__ void llc_store_4rows(unsigned short* p,
                                                unsigned short a, unsigned short b,
                                                unsigned short c, unsigned short d) {
  asm volatile(
    "global_store_short %4, %0, off sc0 sc1\n\t"
    "global_store_short %4, %1, off offset:1024 sc0 sc1\n\t"
    "global_store_short %4, %2, off offset:2048 sc0 sc1\n\t"
    "global_store_short %4, %3, off offset:3072 sc0 sc1"
    :: "v"((unsigned)a), "v"((unsigned)b), "v"((unsigned)c), "v"((unsigned)d), "v"(p)
    : "memory");
}
__device__ __forceinline__ int flag_ld_llc(const int* p) {
  int v; asm volatile("global_load_dword %0, %1, off sc0 sc1\n\ts_waitcnt vmcnt(0)"
                      : "=v"(v) : "v"(p) : "memory"); return v;
}
__device__ __forceinline__ void flag_st_llc(int* p, int v) {
  asm volatile("global_store_dword %0, %1, off sc0 sc1" :: "v"(p), "v"(v) : "memory");
}
__device__ __forceinline__ void drain_vm() {
  asm volatile("s_waitcnt vmcnt(0)" ::: "memory");
}

// ---------------- single fused prep kernel ----------------
#define PREP_BLOCKS 19992
__global__ __launch_bounds__(256) void prep_all(
    const float* __restrict__ x, const float* __restrict__ Wmih, const float* __restrict__ Wmhh,
    const float* __restrict__ Wih, const float* __restrict__ Whh,
    const float* __restrict__ b_d, const float* __restrict__ b_mih, const float* __restrict__ b_mhh,
    const float* __restrict__ b_ih, const float* __restrict__ b_hh,
    unsigned short* __restrict__ Xb, unsigned short* __restrict__ Wmih_b,
    unsigned short* __restrict__ Wmhh_b, unsigned short* __restrict__ W2,
    float* __restrict__ wd2, float* __restrict__ bA, float* __restrict__ bB,
    int* __restrict__ counters) {
  const int blk = blockIdx.x, tid = threadIdx.x;
  if (blk < 16384) {
    int i = blk * 256 + tid;
    float4 v = reinterpret_cast<const float4*>(x)[i];
    ushort4 o; o.x = f2bf(v.x); o.y = f2bf(v.y); o.z = f2bf(v.z); o.w = f2bf(v.w);
    reinterpret_cast<ushort4*>(Xb)[i] = o;
  } else if (blk < 17152) {
    int i = (blk - 16384) * 256 + tid;
    float4 v = reinterpret_cast<const float4*>(Wmih)[i];
    ushort4 o; o.x = f2bf(v.x); o.y = f2bf(v.y); o.z = f2bf(v.z); o.w = f2bf(v.w);
    reinterpret_cast<ushort4*>(Wmih_b)[i] = o;
  } else if (blk < 17920) {
    int i = (blk - 17152) * 256 + tid;
    float4 v = reinterpret_cast<const float4*>(Wmhh)[i];
    ushort4 o; o.x = f2bf(v.x); o.y = f2bf(v.y); o.z = f2bf(v.z); o.w = f2bf(v.w);
    reinterpret_cast<ushort4*>(Wmhh_b)[i] = o;
  } else if (blk < 19968) {
    int i4 = (blk - 17920) * 256 + tid;
    int i = i4 * 4; int n = i >> 10; int k = i & 1023;
    float4 v = (k < 512) ? reinterpret_cast<const float4*>(Wih + n * 512 + k)[0]
                         : reinterpret_cast<const float4*>(Whh + n * 512 + (k - 512))[0];
    ushort4 o; o.x = f2bf(v.x); o.y = f2bf(v.y); o.z = f2bf(v.z); o.w = f2bf(v.w);
    reinterpret_cast<ushort4*>(W2 + i)[0] = o;
  } else if (blk < 19984) {
    int t = (blk - 19968) * 256 + tid;
    if (t < 512) {
      float d = 0.5f * sigm(b_d[t]);
      float c = 1.0f;
      for (int i = 0; i < KHIST; ++i) {
        c *= ((float)i - d) / ((float)i + 1.0f);
        wd2[i * HDIM + t] = c;
      }
    } else if (t < 2048) {
      int n = t - 512;
      bA[n] = b_mih[n] + b_mhh[n];
    } else {
      int n = t - 2048;
      bB[n] = b_ih[n] + b_hh[n];
    }
  } else {
    int i = (blk - 19984) * 256 + tid;
    counters[i] = 0;
  }
}

// ---------------- async persistent recurrent kernel ----------------
// r10 structure; NEW: A blocks compute their GX slice in-register per step
// (48 MFMA vs materialized GXh) — X/Wmih via plain cached loads (read-only,
// hot in L2). acc[g] starts at bias; GX MFMA BEFORE the poll (no dependency);
// recurrent MFMA accumulates into the same registers after the barrier.
__global__ __launch_bounds__(512, 1) void recurrent2(
    const unsigned short* __restrict__ Xb,     // (T x 256 x 512) bf16
    const unsigned short* __restrict__ Wmih,   // (1536 x 512) bf16 N-major
    const unsigned short* __restrict__ Wmhh,   // (1536 x 512) bf16 N-major
    const unsigned short* __restrict__ W2,     // (2048 x 1024) bf16 N-major
    const float* __restrict__ bA,              // (1536)
    const float* __restrict__ bB,              // (2048)
    const float* __restrict__ wd2,             // (32 x 512)
    unsigned short* __restrict__ h1his,        // (16 x 256 x 512) bf16
    unsigned short* __restrict__ h2his,        // (16 x 256 x 512) bf16
    float* __restrict__ sel,                   // (256 x 512) fp32
    const int* __restrict__ length,
    int* __restrict__ counters) {              // aFlags at bs*64, bFlags at 1024+bs*64
  extern __shared__ char lds[];
  const int tid = threadIdx.x;
  const int lane = tid & 63;
  const int wv = tid >> 6;                 // 0..7
  const int q = lane >> 4, r16 = lane & 15;
  const int xcd = (int)blockIdx.x & 7;
  const int bs = xcd >> 1;
  const bool isA = (xcd & 1) == 0;
  const int hs = (int)blockIdx.x >> 3;
  const int hcol = hs * 16 + r16;
  int* aFlags = counters + bs * 64;
  int* bFlags = counters + 1024 + bs * 64;

  if (isA) {
    unsigned short* WA = (unsigned short*)lds;                        // [48][520]
    unsigned short* HI = (unsigned short*)(lds + 48 * WA_STRIDE * 2); // 64KB hist
    for (int idx = tid; idx < 48 * 64; idx += 512) {
      int rowi = idx >> 6, kc = idx & 63;
      int g = rowi >> 4, c = rowi & 15;
      const unsigned short* src = Wmhh + ((size_t)(g * 512 + hs * 16 + c)) * 512 + kc * 8;
      *(short8*)(WA + rowi * WA_STRIDE + kc * 8) = *(const short8*)src;
    }
    for (int idx = tid; idx < 4096; idx += 512)
      ((uint4*)HI)[idx] = (uint4){0, 0, 0, 0};
    float wdr[KHIST];
    #pragma unroll
    for (int l = 0; l < KHIST; ++l) wdr[l] = wd2[l * HDIM + hcol];
    float bAr[3];
    #pragma unroll
    for (int g = 0; g < 3; ++g) bAr[g] = bA[g * 512 + hcol];
    __syncthreads();

    const int mi = wv & 3;
    const int m0 = bs * 64 + mi * 16;
    const int rg = mi * 4 + q;

    for (int s = 0; s < T_STEPS; ++s) {
      floatx4 acc[3];
      #pragma unroll
      for (int g = 0; g < 3; ++g)
        acc[g] = (floatx4){bAr[g], bAr[g], bAr[g], bAr[g]};
      if (wv < 4) {
        // GX slice in-register (static data, BEFORE the poll): 48 MFMA,
        // X row + Wmih slice via plain cached loads (L2-hot)
        const unsigned short* xrow = Xb + ((size_t)s * BATCH + m0 + r16) * IDIM;
        #pragma unroll 4
        for (int kk = 0; kk < 16; ++kk) {
          short8 a = *(const short8*)(xrow + kk * 32 + q * 8);
          #pragma unroll
          for (int g = 0; g < 3; ++g) {
            short8 b = *(const short8*)(Wmih + ((size_t)(g * 512 + hs * 16 + r16)) * 512 + kk * 32 + q * 8);
            acc[g] = __builtin_amdgcn_mfma_f32_16x16x32_bf16(a, b, acc[g], 0, 0, 0);
          }
        }
      }
      if (wv == 0) {
        if (lane < 32) {
          if (s > 0) {
            const int* f = aFlags + lane;
            while (flag_ld_llc(f) < s) __builtin_amdgcn_s_sleep(1);
          }
        } else {
          int tgt = s - (RDEPTH - 1);
          if (tgt > 0) {
            const int* f = bFlags + (lane - 32);
            while (flag_ld_llc(f) < tgt) __builtin_amdgcn_s_sleep(1);
          }
        }
      }
      __syncthreads();
      if (wv < 4) {
        // frac-diff filter (wave-private LDS)
        float f0 = 0.f, f1 = 0.f, f2 = 0.f, f3 = 0.f;
        #pragma unroll
        for (int jj = 1; jj <= KHIST; ++jj) {
          int sl = (s - jj) & (KHIST - 1);
          ushort4 hv = *(const ushort4*)(HI + ((size_t)(sl * 16 + rg) * 16 + r16) * 4);
          float wc = wdr[jj - 1];
          f0 += wc * bf2f(hv.x); f1 += wc * bf2f(hv.y);
          f2 += wc * bf2f(hv.z); f3 += wc * bf2f(hv.w);
        }
        float fj[4] = {f0, f1, f2, f3};
        if (s > 0) {
          const unsigned short* ab = h1his +
              ((size_t)((s - 1) & (RDEPTH - 1)) * BATCH + m0 + r16) * 512 + q * 8;
          short8 af[16];
          llc_load_1k(ab, af);
          #pragma unroll
          for (int kk = 0; kk < 16; ++kk) {
            #pragma unroll
            for (int g = 0; g < 3; ++g) {
              short8 b = *(const short8*)(WA + (size_t)(g * 16 + r16) * WA_STRIDE + kk * 32 + q * 8);
              acc[g] = __builtin_amdgcn_mfma_f32_16x16x32_bf16(af[kk], b, acc[g], 0, 0, 0);
            }
          }
        }
        float c1[4];
        unsigned short h1w[4];
        #pragma unroll
        for (int j = 0; j < 4; ++j) {
          float gI = acc[0][j];
          float gO = acc[1][j];
          float gG = acc[2][j];
          float ig = sigm(gI), og = sigm(gO), cd = tanh_f(gG);
          float c1v = ig * cd - fj[j];
          c1[j] = c1v;
          h1w[j] = f2bf(og * tanh_f(c1v));
        }
        llc_store_4rows(h1his + ((size_t)(s & (RDEPTH - 1)) * BATCH + m0 + q * 4) * 512 + hcol,
                        h1w[0], h1w[1], h1w[2], h1w[3]);
        ushort4 hw;
        hw.x = f2bf(c1[0]); hw.y = f2bf(c1[1]); hw.z = f2bf(c1[2]); hw.w = f2bf(c1[3]);
        *(ushort4*)(HI + ((size_t)((s & (KHIST - 1)) * 16 + rg) * 16 + r16) * 4) = hw;
      }
      drain_vm();
      __syncthreads();
      if (tid == 0)
        flag_st_llc(aFlags + hs, s + 1);
    }
  } else {
    // ---- B block ----
    unsigned short* WB = (unsigned short*)lds;                 // [64][1032]
    float* EX = (float*)(lds + 64 * WB_STRIDE * 2);            // exch [4 mi][4 g][64 lane][4]
    for (int idx = tid; idx < 64 * 128; idx += 512) {
      int rowi = idx >> 7, kc = idx & 127;
      int g = rowi >> 4, c = rowi & 15;
      const unsigned short* src = W2 + ((size_t)(g * 512 + hs * 16 + c)) * 1024 + kc * 8;
      *(short8*)(WB + rowi * WB_STRIDE + kc * 8) = *(const short8*)src;
    }
    const int mi = wv >> 1, kh = wv & 1;
    const int m0 = bs * 64 + mi * 16;
    float c2r[4] = {0.f, 0.f, 0.f, 0.f};
    int lenr[4];
    float bBr[4];
    #pragma unroll
    for (int j = 0; j < 4; ++j) lenr[j] = length[m0 + q * 4 + j];
    #pragma unroll
    for (int g = 0; g < 4; ++g) bBr[g] = bB[g * 512 + hcol];
    __syncthreads();

    for (int t = 0; t < T_STEPS; ++t) {
      if (wv == 0) {
        if (lane < 32) {
          const int* f = aFlags + lane;
          while (flag_ld_llc(f) < t + 1) __builtin_amdgcn_s_sleep(1);   // A done t
        } else if (t > 0) {
          const int* f = bFlags + (lane - 32);
          while (flag_ld_llc(f) < t) __builtin_amdgcn_s_sleep(1);       // B peers done t-1
        }
      }
      __syncthreads();
      floatx4 acc[4];
      #pragma unroll
      for (int g = 0; g < 4; ++g) acc[g] = (floatx4){0.f, 0.f, 0.f, 0.f};
      bool doit = !(kh == 1 && t == 0);
      if (doit) {
        const unsigned short* ab;
        if (kh == 0)
          ab = h1his + ((size_t)(t & (RDEPTH - 1)) * BATCH + m0 + r16) * 512 + q * 8;
        else
          ab = h2his + ((size_t)((t - 1) & (RDEPTH - 1)) * BATCH + m0 + r16) * 512 + q * 8;
        short8 af[16];
        llc_load_1k(ab, af);
        #pragma unroll
        for (int kk = 0; kk < 16; ++kk) {
          #pragma unroll
          for (int g = 0; g < 4; ++g) {
            short8 b = *(const short8*)(WB + (size_t)(g * 16 + r16) * WB_STRIDE + kh * 512 + kk * 32 + q * 8);
            acc[g] = __builtin_amdgcn_mfma_f32_16x16x32_bf16(af[kk], b, acc[g], 0, 0, 0);
          }
        }
      }
      if (kh == 1) {
        #pragma unroll
        for (int g = 0; g < 4; ++g)
          *(floatx4*)(EX + ((size_t)(mi * 4 + g) * 64 + lane) * 4) = acc[g];
      }
      __syncthreads();
      if (kh == 0) {
        #pragma unroll
        for (int g = 0; g < 4; ++g)
          acc[g] += *(const floatx4*)(EX + ((size_t)(mi * 4 + g) * 64 + lane) * 4);
        unsigned short h2w[4];
        #pragma unroll
        for (int j = 0; j < 4; ++j) {
          int row = m0 + q * 4 + j;
          float gi = acc[0][j] + bBr[0];
          float gf = acc[1][j] + bBr[1];
          float gg = acc[2][j] + bBr[2];
          float go = acc[3][j] + bBr[3];
          float c2n = sigm(gf) * c2r[j] + sigm(gi) * tanh_f(gg);
          c2r[j] = c2n;
          float h2n = tanh_f(sigm(go) * tanh_f(c2n));
          h2w[j] = f2bf(h2n);
          if (lenr[j] == t) sel[(size_t)row * 512 + hcol] = h2n;
        }
        llc_store_4rows(h2his + ((size_t)(t & (RDEPTH - 1)) * BATCH + m0 + q * 4) * 512 + hcol,
                        h2w[0], h2w[1], h2w[2], h2w[3]);
      }
      drain_vm();
      __syncthreads();
      if (tid == 0)
        flag_st_llc(bFlags + hs, t + 1);
    }
  }
}

// ---------------- output head ----------------
__global__ void out_head_kernel(const float* __restrict__ sel, const float* __restrict__ Wout,
                                const float* __restrict__ bout, float* __restrict__ out) {
  int b = blockIdx.x, lane = threadIdx.x;   // 256 blocks x 64 threads
  float acc[5] = {0.f, 0.f, 0.f, 0.f, 0.f};
  for (int j = lane; j < HDIM; j += 64) {
    float x = sel[(size_t)b * HDIM + j];
    #pragma unroll
    for (int o = 0; o < 5; ++o) acc[o] += x * Wout[o * HDIM + j];
  }
  #pragma unroll
  for (int o = 0; o < 5; ++o)
    for (int off = 32; off > 0; off >>= 1) acc[o] += __shfl_down(acc[o], off);
  if (lane == 0) {
    float v[5]; float m = -1e30f;
    #pragma unroll
    for (int o = 0; o < 5; ++o) { v[o] = acc[o] + bout[o]; m = fmaxf(m, v[o]); }
    float s = 0.f;
    #pragma unroll
    for (int o = 0; o < 5; ++o) s += __expf(v[o] - m);
    float l = logf(s) + m;
    #pragma unroll
    for (int o = 0; o < 5; ++o) out[b * 5 + o] = v[o] - l;
  }
}

// ---------------- launch ----------------
extern "C" void kernel_launch(void* const* d_in, const int* in_sizes, int n_in,
                              void* d_out, int out_size, void* d_ws, size_t ws_size,
                              hipStream_t stream) {
  const float* x      = (const float*)d_in[0];
  const int*   length = (const int*)d_in[1];
  const float* b_d    = (const float*)d_in[2];
  const float* W_mih  = (const float*)d_in[3];
  const float* W_mhh  = (const float*)d_in[4];
  const float* b_mih  = (const float*)d_in[5];
  const float* b_mhh  = (const float*)d_in[6];
  const float* W_ih   = (const float*)d_in[7];
  const float* W_hh   = (const float*)d_in[8];
  const float* b_ih   = (const float*)d_in[9];
  const float* b_hh   = (const float*)d_in[10];
  const float* W_out  = (const float*)d_in[11];
  const float* b_out  = (const float*)d_in[12];
  float* out = (float*)d_out;

  char* ws = (char*)d_ws;
  size_t off = 0;
  auto take = [&](size_t bytes) -> char* {
    char* p = ws + off;
    off += (bytes + 255) & ~(size_t)255;
    return p;
  };

  unsigned short* Xb     = (unsigned short*)take((size_t)T_STEPS * BATCH * IDIM * 2);
  unsigned short* Wmih_b = (unsigned short*)take(1536 * 512 * 2);
  unsigned short* Wmhh_b = (unsigned short*)take(1536 * 512 * 2);
  unsigned short* W2_b   = (unsigned short*)take(2048 * 1024 * 2);
  float* bA  = (float*)take(1536 * 4);
  float* bB  = (float*)take(2048 * 4);
  float* wd2 = (float*)take(KHIST * HDIM * 4);
  unsigned short* h1his = (unsigned short*)take((size_t)RDEPTH * BATCH * 512 * 2);
  unsigned short* h2his = (unsigned short*)take((size_t)RDEPTH * BATCH * 512 * 2);
  float* sel = (float*)take((size_t)BATCH * HDIM * 4);
  int* counters = (int*)take(8192);
  if (off > ws_size) return;  // workspace too small -> loud validation failure

  prep_all<<<PREP_BLOCKS, 256, 0, stream>>>(x, W_mih, W_mhh, W_ih, W_hh,
                                            b_d, b_mih, b_mhh, b_ih, b_hh,
                                            Xb, Wmih_b, Wmhh_b, W2_b, wd2, bA, bB, counters);

  hipFuncSetAttribute((const void*)recurrent2, hipFuncAttributeMaxDynamicSharedMemorySize, LDS_BYTES);
  void* kargs[] = { (void*)&Xb, (void*)&Wmih_b, (void*)&Wmhh_b, (void*)&W2_b,
                    (void*)&bA, (void*)&bB, (void*)&wd2,
                    (void*)&h1his, (void*)&h2his, (void*)&sel, (void*)&length,
                    (void*)&counters };
  hipLaunchCooperativeKernel((void*)recurrent2, dim3(256), dim3(512), kargs, LDS_BYTES, stream);

  out_head_kernel<<<BATCH, 64, 0, stream>>>(sel, W_out, b_out, out);
}